// Round 4
// baseline (323.087 us; speedup 1.0000x reference)
//
#include <hip/hip_runtime.h>

// MultiSpectralDCTLayer: Y = W @ X @ W^T per (b,c) tile, then radial band mask.
// XOR bug in the mask => only c=0 (s<196) and c=1 (s>=196) keep entries, where
// s = (i^2)+(j^2) with ^ = bitwise XOR. Groups 2..63 are constant 1e-8.
//
// Grid: 512 compute blocks first (128 tiles x 4 row-chunks of 28 rows), then
// 3968 pure-fill blocks, one kernel so fills overlap compute.
// LDS = 24.5 KB (X panel + U) -> 6 blocks/CU for BOTH paths (round-2 had
// 64.5 KB -> 2 blocks/CU, which serialized compute in front of the fill).

#define SIZE  112
#define TILE  (SIZE * SIZE)    // 12544
#define TILE4 (TILE / 4)       // 3136
#define ROW4  (SIZE / 4)       // 28
#define NCOMPUTE 512
#define FILLV 1e-8f

typedef float floatx4 __attribute__((ext_vector_type(4)));  // native vec for nontemporal

#define DOT4(a, b) ((a).x*(b).x + (a).y*(b).y + (a).z*(b).z + (a).w*(b).w)

__global__ __launch_bounds__(256)
void dct_band_kernel(const float* __restrict__ x,
                     const float* __restrict__ W,
                     float* __restrict__ out)
{
    const int tid = threadIdx.x;
    const int blk = blockIdx.x;

    if (blk >= NCOMPUTE) {
        // ---- pure fill: groups c>=2 are 1e-8 everywhere ----
        const int f = blk - NCOMPUTE;
        const int b = f / 62;
        const int c = 2 + f % 62;
        floatx4* o4 = (floatx4*)(out + (size_t)(b * 64 + c) * TILE);
        const floatx4 v = {FILLV, FILLV, FILLV, FILLV};
        #pragma unroll
        for (int n = 0; n < 13; ++n) {
            int e = tid + n * 256;
            if (e < TILE4) __builtin_nontemporal_store(v, o4 + e);
        }
        return;
    }

    // ---- compute path ----
    __shared__ float4 Xs[784];    // one 28-row K-panel of X: 12544 B
    __shared__ float4 Usm[784];   // U[di][l4], row stride 28 float4s: 12544 B

    const int q  = blk & 3;          // row chunk: rows i0..i0+27
    const int t  = blk >> 2;         // tile 0..127
    const int b  = t >> 1;
    const int c  = t & 1;
    const int i0 = 28 * q;
    const size_t tOff = (size_t)(b * 64 + c) * TILE;
    const float4* x4 = (const float4*)(x + tOff);

    // Stage A: U[i0+di][l] = sum_k W[i0+di][k] * X[k][l], K in 4 panels of 28.
    // thread (diq, l4): 4 di rows x 4 l cols; 196 active threads.
    const int diq = tid / 28;
    const int l4  = tid % 28;
    float4 u0 = make_float4(0,0,0,0), u1 = u0, u2 = u0, u3 = u0;

    for (int kp = 0; kp < 4; ++kp) {
        // load X panel (rows kp*28 .. kp*28+27) -> LDS, coalesced float4
        #pragma unroll
        for (int n = 0; n < 4; ++n) {
            int e = tid + n * 256;
            if (e < 784) Xs[e] = x4[kp * 784 + e];
        }
        __syncthreads();

        if (tid < 196) {
            const float* wr0 = W + (i0 + 4 * diq) * SIZE + kp * 28;
            const float* wr1 = wr0 + SIZE;
            const float* wr2 = wr1 + SIZE;
            const float* wr3 = wr2 + SIZE;
            #pragma unroll 4
            for (int k = 0; k < 28; ++k) {
                float4 xv = Xs[k * 28 + l4];                      // LDS broadcast
                float w0 = wr0[k], w1 = wr1[k], w2 = wr2[k], w3 = wr3[k]; // L1
                u0.x += w0 * xv.x; u0.y += w0 * xv.y; u0.z += w0 * xv.z; u0.w += w0 * xv.w;
                u1.x += w1 * xv.x; u1.y += w1 * xv.y; u1.z += w1 * xv.z; u1.w += w1 * xv.w;
                u2.x += w2 * xv.x; u2.y += w2 * xv.y; u2.z += w2 * xv.z; u2.w += w2 * xv.w;
                u3.x += w3 * xv.x; u3.y += w3 * xv.y; u3.z += w3 * xv.z; u3.w += w3 * xv.w;
            }
        }
        __syncthreads();   // Xs reads done before next panel overwrites
    }

    if (tid < 196) {
        const int ub = 4 * diq * 28 + l4;
        Usm[ub]      = u0;
        Usm[ub + 28] = u1;
        Usm[ub + 56] = u2;
        Usm[ub + 84] = u3;
    }
    __syncthreads();

    // Stage B: Y[i][j] = sum_l U[i][l] * W[j][l], then mask + store.
    // thread (dq, jq): 4 i rows x 4 j cols. U broadcast from LDS; W rows
    // walked sequentially from L1 (W is 50 KB, shared by all blocks).
    if (tid < 196) {
        const int dq = tid / 28;
        const int jq = tid % 28;
        float acc[4][4];
        #pragma unroll
        for (int a = 0; a < 4; ++a)
            #pragma unroll
            for (int d = 0; d < 4; ++d) acc[a][d] = 0.f;

        const float4* Ur = Usm + 4 * dq * 28;
        const float4* W4 = (const float4*)W;
        const float4* w0 = W4 + (4 * jq + 0) * ROW4;
        const float4* w1 = W4 + (4 * jq + 1) * ROW4;
        const float4* w2 = W4 + (4 * jq + 2) * ROW4;
        const float4* w3 = W4 + (4 * jq + 3) * ROW4;
        #pragma unroll 2
        for (int l = 0; l < 28; ++l) {
            float4 uv0 = Ur[l], uv1 = Ur[l + 28], uv2 = Ur[l + 56], uv3 = Ur[l + 84];
            float4 wv0 = w0[l], wv1 = w1[l], wv2 = w2[l], wv3 = w3[l];
            acc[0][0] += DOT4(uv0, wv0); acc[0][1] += DOT4(uv0, wv1);
            acc[0][2] += DOT4(uv0, wv2); acc[0][3] += DOT4(uv0, wv3);
            acc[1][0] += DOT4(uv1, wv0); acc[1][1] += DOT4(uv1, wv1);
            acc[1][2] += DOT4(uv1, wv2); acc[1][3] += DOT4(uv1, wv3);
            acc[2][0] += DOT4(uv2, wv0); acc[2][1] += DOT4(uv2, wv1);
            acc[2][2] += DOT4(uv2, wv2); acc[2][3] += DOT4(uv2, wv3);
            acc[3][0] += DOT4(uv3, wv0); acc[3][1] += DOT4(uv3, wv1);
            acc[3][2] += DOT4(uv3, wv2); acc[3][3] += DOT4(uv3, wv3);
        }

        const int j0 = 4 * jq;
        const bool g1 = (c != 0);
        #pragma unroll
        for (int mi = 0; mi < 4; ++mi) {
            const int i  = i0 + 4 * dq + mi;
            const int xi = i ^ 2;
            float4 res;
            res.x = (((xi + ((j0 + 0) ^ 2)) < 196) != g1) ? acc[mi][0] : FILLV;
            res.y = (((xi + ((j0 + 1) ^ 2)) < 196) != g1) ? acc[mi][1] : FILLV;
            res.z = (((xi + ((j0 + 2) ^ 2)) < 196) != g1) ? acc[mi][2] : FILLV;
            res.w = (((xi + ((j0 + 3) ^ 2)) < 196) != g1) ? acc[mi][3] : FILLV;
            ((float4*)(out + tOff + (size_t)i * SIZE))[jq] = res;
        }
    }
}

extern "C" void kernel_launch(void* const* d_in, const int* in_sizes, int n_in,
                              void* d_out, int out_size, void* d_ws, size_t ws_size,
                              hipStream_t stream) {
    const float* x = (const float*)d_in[0];
    const float* W = (const float*)d_in[1];
    float* out = (float*)d_out;
    (void)in_sizes; (void)n_in; (void)out_size; (void)d_ws; (void)ws_size;
    dct_band_kernel<<<dim3(NCOMPUTE + 64 * 62), dim3(256), 0, stream>>>(x, W, out);
}